// Round 3
// baseline (2777.757 us; speedup 1.0000x reference)
//
#include <hip/hip_runtime.h>
#include <cstdint>
#include <cstddef>

// ============================================================================
// LSTM forecaster, MI355X — R3: R2 data-flow pipeline with SYSTEM-scope
// communication. R2 evidence (FETCH ~= 1 MB/step = one group-slice per XCD)
// showed agent-scope poll loads were L2-cached; consumers that polled early
// cached the NaN sentinel in their non-coherent XCD L2 and then waited on
// capacity eviction (~3.8 us/step). SYSTEM scope (sc0 sc1) forces polls and
// publishes through the coherent LLC point: deterministic ~LLC-latency sync.
// ============================================================================

typedef __bf16 bf16x8 __attribute__((ext_vector_type(8)));
typedef float  f32x4  __attribute__((ext_vector_type(4)));

static constexpr unsigned long long SENT = 0x7FC07FC07FC07FC0ULL;  // 4x bf16 NaN

// ---- workspace layout (bytes) ----
static constexpr size_t SZ_HALL = (size_t)705 * 128 * 512 * 2;  // h slots 0..704
static constexpr size_t SZ_WCAT = (size_t)2048 * 576 * 2;       // [Whh | Wfuse] bf16
static constexpr size_t SZ_WIH  = (size_t)2048 * 512 * 2;       // Wih bf16 (AR phase)
static constexpr size_t SZ_DECW = (size_t)64 * 512 * 2;         // dec_W bf16
static constexpr size_t SZ_XT   = (size_t)512 * 128 * 64 * 2;   // x transposed [t][b][c]
static constexpr size_t OFF_HALL = 0;
static constexpr size_t OFF_WCAT = OFF_HALL + SZ_HALL;
static constexpr size_t OFF_WIH  = OFF_WCAT + SZ_WCAT;
static constexpr size_t OFF_DECW = OFF_WIH + SZ_WIH;
static constexpr size_t OFF_XT   = OFF_DECW + SZ_DECW;
static constexpr size_t OFF_B2   = OFF_XT + SZ_XT;              // 2048 f32
static constexpr size_t OFF_BAR_ = OFF_B2 + 2048 * 4;           // b_ar 2048 f32
static constexpr size_t WS_NEEDED = OFF_BAR_ + 2048 * 4;

__device__ __forceinline__ float sigm(float x) { return 1.f / (1.f + __expf(-x)); }
__device__ __forceinline__ float tanh_fast(float x) {
  // tanh(x) = 1 - 2/(e^{2x}+1); exp overflow -> +1, underflow -> -1 (correct limits)
  return 1.f - 2.f / (__expf(2.f * x) + 1.f);
}

// ---------------------------------------------------------------------------
// setup0: conversions + h slot0 zeros + h slots 1..704 NaN sentinel fill.
// Rebuilt every call (ws re-poisoned to 0xAA; 0xAAAA is a legit bf16 value,
// so the NaN fill is mandatory).
// ---------------------------------------------------------------------------
__global__ void __launch_bounds__(256)
setup0(const float* __restrict__ x, const float* __restrict__ Wih,
       const float* __restrict__ Whh, const float* __restrict__ bih,
       const float* __restrict__ bhh, const float* __restrict__ decW,
       __bf16* __restrict__ xT, __bf16* __restrict__ Wih_bf,
       __bf16* __restrict__ Wcat, __bf16* __restrict__ decW_bf,
       float* __restrict__ b_ar, __bf16* __restrict__ h_all)
{
  size_t gid = (size_t)blockIdx.x * blockDim.x + threadIdx.x;
  size_t gsz = (size_t)gridDim.x * blockDim.x;
  // xT[t][b][c] = bf16(x[b][t][c])
  for (size_t i = gid; i < 4194304u; i += gsz) {
    size_t t = i >> 13, b = (i >> 6) & 127u, c = i & 63u;
    xT[i] = (__bf16)x[(b * 512 + t) * 64 + c];
  }
  for (size_t i = gid; i < 1048576u; i += gsz) Wih_bf[i] = (__bf16)Wih[i];
  for (size_t i = gid; i < 1048576u; i += gsz) {
    size_t r = i >> 9, k = i & 511u;
    Wcat[r * 576 + k] = (__bf16)Whh[i];          // cols 0..511 = Whh
  }
  for (size_t i = gid; i < 32768u; i += gsz) decW_bf[i] = (__bf16)decW[i];
  for (size_t i = gid; i < 2048u; i += gsz) b_ar[i] = bih[i] + bhh[i];
  unsigned long long* hp = (unsigned long long*)h_all;
  for (size_t i = gid; i < 16384u; i += gsz) hp[i] = 0ULL;               // slot 0 = 0
  for (size_t i = 16384u + gid; i < 11550720u; i += gsz) hp[i] = SENT;   // slots 1..704
}

// ---------------------------------------------------------------------------
// setup1: Wfuse = Wih @ enc_W  ->  Wcat cols 512..575 ; b2 = bih+bhh+Wih@enc_b
// ---------------------------------------------------------------------------
__global__ void __launch_bounds__(64)
setup1(const float* __restrict__ Wih, const float* __restrict__ encW,
       const float* __restrict__ encb, const float* __restrict__ bih,
       const float* __restrict__ bhh, __bf16* __restrict__ Wcat,
       float* __restrict__ b2)
{
  int r = blockIdx.x;        // 0..2047
  int c = threadIdx.x;       // 0..63
  const float* wr = Wih + (size_t)r * 512;
  float acc = 0.f;
  for (int k = 0; k < 512; ++k) acc += wr[k] * encW[(size_t)k * 64 + c];
  Wcat[(size_t)r * 576 + 512 + c] = (__bf16)acc;
  float p = 0.f;
  for (int kk = 0; kk < 8; ++kk) { int k = kk * 64 + c; p += wr[k] * encb[k]; }
  for (int off = 32; off > 0; off >>= 1) p += __shfl_down(p, off);
  if (c == 0) b2[r] = bih[r] + bhh[r] + p;
}

// ---------------------------------------------------------------------------
// One LSTM step, data-flow synchronized via SYSTEM-scope atomics.
// block = 256 thr (4 waves, one gate each). bid = g*32+fb.
// ---------------------------------------------------------------------------
template<bool MAIN>
__device__ __forceinline__ void lstm_step(
    unsigned t, int tid, int wv, int lane, int b0, int f0,
    const bf16x8 (&wf)[18], float bv,
    __bf16* __restrict__ h_all, const __bf16* __restrict__ xT,
    f32x4& creg, __bf16 (*A)[584], float (*ex)[16][17])
{
  const int n16 = lane & 15, quad = lane >> 4;

  // ---- x prefetch (normal cached load; L2-resident) ----
  uint4 xv;
  if (MAIN && tid < 128)
    xv = *(const uint4*)(xT + (size_t)(t - 1) * 8192 +
                         (size_t)(b0 + (tid >> 3)) * 64 + (tid & 7) * 8);

  // ---- poll h_{t-1}: 8 x 8B pieces per thread, selective re-load.
  //      SYSTEM scope: bypass the (non-coherent) XCD L2, read the LLC. ----
  const unsigned long long* src = (const unsigned long long*)
      (h_all + (size_t)(t - 1) * 65536 + (size_t)(b0 + (tid >> 4)) * 512) +
      (size_t)(tid & 15) * 8;
  unsigned long long v[8];
  unsigned bad = 0xFFu;
  do {
    unsigned nb = 0;
    #pragma unroll
    for (int i = 0; i < 8; ++i)
      if (bad & (1u << i))
        v[i] = __hip_atomic_load(src + i, __ATOMIC_RELAXED, __HIP_MEMORY_SCOPE_SYSTEM);
    #pragma unroll
    for (int i = 0; i < 8; ++i)
      if ((bad & (1u << i)) && v[i] == SENT) nb |= 1u << i;
    bad = nb;
  } while (bad);

  // ---- stage A (data already in registers from the poll) ----
  {
    unsigned long long* ad = (unsigned long long*)&A[tid >> 4][(tid & 15) * 32];
    #pragma unroll
    for (int i = 0; i < 8; ++i) ad[i] = v[i];
  }
  if (MAIN && tid < 128)
    *(uint4*)(&A[tid >> 3][512 + (tid & 7) * 8]) = xv;
  __syncthreads();

  // ---- MFMA: wave wv = gate wv; bias pre-loaded into accumulator ----
  if (MAIN || wv != 1) {
    f32x4 a0 = {bv, bv, bv, bv}, a1 = {0.f, 0.f, 0.f, 0.f};
    const __bf16* arow = &A[n16][quad * 8];
    #pragma unroll
    for (int kc = 0; kc < (MAIN ? 18 : 16); ++kc) {
      bf16x8 af = *(const bf16x8*)(arow + kc * 32);
      if (kc & 1) a1 = __builtin_amdgcn_mfma_f32_16x16x32_bf16(af, wf[kc], a1, 0, 0, 0);
      else        a0 = __builtin_amdgcn_mfma_f32_16x16x32_bf16(af, wf[kc], a0, 0, 0, 0);
    }
    a0 += a1;
    #pragma unroll
    for (int r = 0; r < 4; ++r) ex[wv][n16][quad * 4 + r] = a0[r];  // [gate][feat][batch]
  }
  __syncthreads();

  // ---- gates: 16 lanes per wave each produce one 8B piece (4 feats x 1 batch) ----
  if (lane < 16) {
    const int em = wv * 4 + (lane >> 2), p = lane & 3;
    unsigned long long pk = 0;
    #pragma unroll
    for (int j = 0; j < 4; ++j) {
      const int ef = p * 4 + j;
      float ig = sigm(ex[0][ef][em]);
      float gg = tanh_fast(ex[2][ef][em]);
      float og = sigm(ex[3][ef][em]);
      float c2;
      if (MAIN) { float fg = sigm(ex[1][ef][em]); c2 = fg * creg[j] + ig * gg; creg[j] = c2; }
      else      { c2 = ig * gg; }               // AR: zero state
      float h2 = og * tanh_fast(c2);
      __bf16 hb = (__bf16)h2;
      pk |= (unsigned long long)__builtin_bit_cast(unsigned short, hb) << (16 * j);
    }
    unsigned long long* dst = (unsigned long long*)
        (h_all + (size_t)t * 65536 + (size_t)(b0 + em) * 512 + f0) + p;
    __hip_atomic_store(dst, pk, __ATOMIC_RELAXED, __HIP_MEMORY_SCOPE_SYSTEM);
  }
  // no trailing barrier: next step's LDS writes are ordered by the two
  // __syncthreads above; h publication is the atomic store itself.
}

__global__ void __launch_bounds__(256)
lstm_persist(const __bf16* __restrict__ xT, const __bf16* __restrict__ Wcat,
             const __bf16* __restrict__ Wih_bf, const float* __restrict__ b2,
             const float* __restrict__ b_ar, __bf16* __restrict__ h_all)
{
  const int bid = blockIdx.x;
  const int g = bid >> 5, fb = bid & 31;
  const int b0 = g * 16, f0 = fb * 16;
  const int tid = threadIdx.x;
  const int wv = tid >> 6, lane = tid & 63;
  const int n16 = lane & 15, quad = lane >> 4;

  __shared__ __align__(16) __bf16 A[16][584];   // 16 batch rows x (512 h + 64 x + pad)
  __shared__ float ex[4][16][17];               // gate exchange

  // persistent weight fragments (VGPR-resident all 704 steps)
  bf16x8 wf[18];
  {
    const __bf16* wrow = Wcat + (size_t)(wv * 512 + f0 + n16) * 576 + quad * 8;
    #pragma unroll
    for (int kc = 0; kc < 18; ++kc) wf[kc] = *(const bf16x8*)(wrow + kc * 32);
  }
  float bvm = b2[wv * 512 + f0 + n16];

  f32x4 creg = {0.f, 0.f, 0.f, 0.f};   // cell state (lanes 0..15 of each wave)

  for (unsigned t = 1; t <= 512; ++t)
    lstm_step<true>(t, tid, wv, lane, b0, f0, wf, bvm, h_all, xT, creg, A, ex);

  { // AR phase: h feeds Wih with zero recurrent state
    const __bf16* wrow = Wih_bf + (size_t)(wv * 512 + f0 + n16) * 512 + quad * 8;
    #pragma unroll
    for (int kc = 0; kc < 16; ++kc) wf[kc] = *(const bf16x8*)(wrow + kc * 32);
  }
  float bva = b_ar[wv * 512 + f0 + n16];
  for (unsigned t = 513; t <= 704; ++t)
    lstm_step<false>(t, tid, wv, lane, b0, f0, wf, bva, h_all, xT, creg, A, ex);
}

// ---------------------------------------------------------------------------
// final_proj: out[b][j][c] = h_slot[j+2][b][:] @ dec_W.T + dec_b, j=0..702.
// ---------------------------------------------------------------------------
__global__ void __launch_bounds__(256)
final_proj(const __bf16* __restrict__ h_all, const __bf16* __restrict__ decW_bf,
           const float* __restrict__ decb, float* __restrict__ out)
{
  const int bi = blockIdx.x;               // 0..702
  const int tid = threadIdx.x;
  const int wv = tid >> 6, lane = tid & 63;
  const int n16 = lane & 15, quad = lane >> 4;
  const size_t r0 = 256 + (size_t)bi * 128 + (size_t)wv * 32;

  f32x4 acc[2][4];
  #pragma unroll
  for (int mt = 0; mt < 2; ++mt)
    #pragma unroll
    for (int nt = 0; nt < 4; ++nt) acc[mt][nt] = f32x4{0.f, 0.f, 0.f, 0.f};

  const __bf16* arow0 = h_all + (r0 + n16) * 512 + quad * 8;
  const __bf16* arow1 = arow0 + 16 * 512;
  const __bf16* brow  = decW_bf + (size_t)n16 * 512 + quad * 8;

  #pragma unroll
  for (int kc = 0; kc < 16; ++kc) {
    bf16x8 a0 = *(const bf16x8*)(arow0 + kc * 32);
    bf16x8 a1 = *(const bf16x8*)(arow1 + kc * 32);
    #pragma unroll
    for (int nt = 0; nt < 4; ++nt) {
      bf16x8 b = *(const bf16x8*)(brow + (size_t)nt * 8192 + kc * 32);
      acc[0][nt] = __builtin_amdgcn_mfma_f32_16x16x32_bf16(a0, b, acc[0][nt], 0, 0, 0);
      acc[1][nt] = __builtin_amdgcn_mfma_f32_16x16x32_bf16(a1, b, acc[1][nt], 0, 0, 0);
    }
  }
  #pragma unroll
  for (int mt = 0; mt < 2; ++mt)
    #pragma unroll
    for (int nt = 0; nt < 4; ++nt)
      #pragma unroll
      for (int r = 0; r < 4; ++r) {
        size_t R = r0 + mt * 16 + quad * 4 + r;      // h_all row
        int slot = (int)(R >> 7), b = (int)(R & 127);
        int j = slot - 2;
        int c = nt * 16 + n16;
        out[((size_t)b * 703 + j) * 64 + c] = acc[mt][nt][r] + decb[c];
      }
}

// ---------------------------------------------------------------------------
extern "C" void kernel_launch(void* const* d_in, const int* in_sizes, int n_in,
                              void* d_out, int out_size, void* d_ws, size_t ws_size,
                              hipStream_t stream)
{
  const float* x    = (const float*)d_in[0];
  const float* encW = (const float*)d_in[1];
  const float* encb = (const float*)d_in[2];
  const float* Wih  = (const float*)d_in[3];
  const float* Whh  = (const float*)d_in[4];
  const float* bih  = (const float*)d_in[5];
  const float* bhh  = (const float*)d_in[6];
  const float* decW = (const float*)d_in[7];
  const float* decb = (const float*)d_in[8];
  float* out = (float*)d_out;

  if (ws_size < WS_NEEDED) return;

  char* ws = (char*)d_ws;
  __bf16* h_all   = (__bf16*)(ws + OFF_HALL);
  __bf16* Wcat    = (__bf16*)(ws + OFF_WCAT);
  __bf16* Wih_bf  = (__bf16*)(ws + OFF_WIH);
  __bf16* decW_bf = (__bf16*)(ws + OFF_DECW);
  __bf16* xT      = (__bf16*)(ws + OFF_XT);
  float*  b2      = (float*)(ws + OFF_B2);
  float*  b_ar    = (float*)(ws + OFF_BAR_);

  hipLaunchKernelGGL(setup0, dim3(2048), dim3(256), 0, stream,
                     x, Wih, Whh, bih, bhh, decW, xT, Wih_bf, Wcat, decW_bf,
                     b_ar, h_all);
  hipLaunchKernelGGL(setup1, dim3(2048), dim3(64), 0, stream,
                     Wih, encW, encb, bih, bhh, Wcat, b2);
  hipLaunchKernelGGL(lstm_persist, dim3(256), dim3(256), 0, stream,
                     xT, Wcat, Wih_bf, b2, b_ar, h_all);
  hipLaunchKernelGGL(final_proj, dim3(703), dim3(256), 0, stream,
                     h_all, decW_bf, decb, out);
}

// Round 4
// 2534.706 us; speedup vs baseline: 1.0959x; 1.0959x over previous
//
#include <hip/hip_runtime.h>
#include <cstdint>
#include <cstddef>

// ============================================================================
// LSTM forecaster, MI355X — R4: R2/R3 data-flow pipeline with merged blocks.
// R3 evidence: agent==system scope bit-identical -> comm cost is structural:
// 32-producer gather, 8 serialized poll pieces/thread, 4 waves/CU. R4 merges
// 4 feature-blocks into one 1024-thread block: group = 8 producers, poll = 2
// pieces/thread, 16 waves/CU for latency hiding. Sync is still pure data-flow
// (bf16 NaN sentinel, 8B agent-scope atomics), no fences, no barriers.
// ============================================================================

typedef __bf16 bf16x8 __attribute__((ext_vector_type(8)));
typedef float  f32x4  __attribute__((ext_vector_type(4)));

static constexpr unsigned long long SENT = 0x7FC07FC07FC07FC0ULL;  // 4x bf16 NaN

// ---- workspace layout (bytes) ----
static constexpr size_t SZ_HALL = (size_t)705 * 128 * 512 * 2;  // h slots 0..704
static constexpr size_t SZ_WCAT = (size_t)2048 * 576 * 2;       // [Whh | Wfuse] bf16
static constexpr size_t SZ_WIH  = (size_t)2048 * 512 * 2;       // Wih bf16 (AR phase)
static constexpr size_t SZ_DECW = (size_t)64 * 512 * 2;         // dec_W bf16
static constexpr size_t SZ_XT   = (size_t)512 * 128 * 64 * 2;   // x transposed [t][b][c]
static constexpr size_t OFF_HALL = 0;
static constexpr size_t OFF_WCAT = OFF_HALL + SZ_HALL;
static constexpr size_t OFF_WIH  = OFF_WCAT + SZ_WCAT;
static constexpr size_t OFF_DECW = OFF_WIH + SZ_WIH;
static constexpr size_t OFF_XT   = OFF_DECW + SZ_DECW;
static constexpr size_t OFF_B2   = OFF_XT + SZ_XT;              // 2048 f32
static constexpr size_t OFF_BAR_ = OFF_B2 + 2048 * 4;           // b_ar 2048 f32
static constexpr size_t WS_NEEDED = OFF_BAR_ + 2048 * 4;

__device__ __forceinline__ float sigm(float x) { return 1.f / (1.f + __expf(-x)); }
__device__ __forceinline__ float tanh_fast(float x) {
  return 1.f - 2.f / (__expf(2.f * x) + 1.f);  // correct +/-1 limits on over/underflow
}

// ---------------------------------------------------------------------------
// setup0: conversions + h slot0 zeros + h slots 1..704 NaN sentinel fill.
// (ws re-poisoned to 0xAA each run; 0xAAAA is a legit bf16 -> NaN fill needed.)
// ---------------------------------------------------------------------------
__global__ void __launch_bounds__(256)
setup0(const float* __restrict__ x, const float* __restrict__ Wih,
       const float* __restrict__ Whh, const float* __restrict__ bih,
       const float* __restrict__ bhh, const float* __restrict__ decW,
       __bf16* __restrict__ xT, __bf16* __restrict__ Wih_bf,
       __bf16* __restrict__ Wcat, __bf16* __restrict__ decW_bf,
       float* __restrict__ b_ar, __bf16* __restrict__ h_all)
{
  size_t gid = (size_t)blockIdx.x * blockDim.x + threadIdx.x;
  size_t gsz = (size_t)gridDim.x * blockDim.x;
  for (size_t i = gid; i < 4194304u; i += gsz) {          // xT[t][b][c] = x[b][t][c]
    size_t t = i >> 13, b = (i >> 6) & 127u, c = i & 63u;
    xT[i] = (__bf16)x[(b * 512 + t) * 64 + c];
  }
  for (size_t i = gid; i < 1048576u; i += gsz) Wih_bf[i] = (__bf16)Wih[i];
  for (size_t i = gid; i < 1048576u; i += gsz) {
    size_t r = i >> 9, k = i & 511u;
    Wcat[r * 576 + k] = (__bf16)Whh[i];                   // cols 0..511 = Whh
  }
  for (size_t i = gid; i < 32768u; i += gsz) decW_bf[i] = (__bf16)decW[i];
  for (size_t i = gid; i < 2048u; i += gsz) b_ar[i] = bih[i] + bhh[i];
  unsigned long long* hp = (unsigned long long*)h_all;
  for (size_t i = gid; i < 16384u; i += gsz) hp[i] = 0ULL;               // slot 0 = 0
  for (size_t i = 16384u + gid; i < 11550720u; i += gsz) hp[i] = SENT;   // slots 1..704
}

// ---------------------------------------------------------------------------
// setup1: Wfuse = Wih @ enc_W -> Wcat cols 512..575 ; b2 = bih+bhh+Wih@enc_b
// ---------------------------------------------------------------------------
__global__ void __launch_bounds__(64)
setup1(const float* __restrict__ Wih, const float* __restrict__ encW,
       const float* __restrict__ encb, const float* __restrict__ bih,
       const float* __restrict__ bhh, __bf16* __restrict__ Wcat,
       float* __restrict__ b2)
{
  int r = blockIdx.x;        // 0..2047
  int c = threadIdx.x;       // 0..63
  const float* wr = Wih + (size_t)r * 512;
  float acc = 0.f;
  for (int k = 0; k < 512; ++k) acc += wr[k] * encW[(size_t)k * 64 + c];
  Wcat[(size_t)r * 576 + 512 + c] = (__bf16)acc;
  float p = 0.f;
  for (int kk = 0; kk < 8; ++kk) { int k = kk * 64 + c; p += wr[k] * encb[k]; }
  for (int off = 32; off > 0; off >>= 1) p += __shfl_down(p, off);
  if (c == 0) b2[r] = bih[r] + bhh[r] + p;
}

// ---------------------------------------------------------------------------
// One LSTM step. block = 1024 thr (16 waves). Wave wv: gate = wv&3,
// feature 16-block fsub = wv>>2 (features f0+fsub*16 .. +16 of this block's
// 64). Gate math + publish: threads tid<256 (em = tid>>4 batch, p = tid&15 ->
// features p*4..p*4+3).
// ---------------------------------------------------------------------------
template<bool MAIN>
__device__ __forceinline__ void lstm_step(
    unsigned t, int tid, int wv, int lane, int b0, int f0,
    const bf16x8 (&wf)[18], float bv,
    __bf16* __restrict__ h_all, const __bf16* __restrict__ xT,
    f32x4& creg, __bf16 (*A)[584], float (*ex)[64][17])
{
  const int n16 = lane & 15, quad = lane >> 4;
  const int gate = wv & 3, fsub = wv >> 2;

  // ---- x prefetch (overlaps the poll) ----
  uint4 xv;
  if (MAIN && tid < 128)
    xv = *(const uint4*)(xT + (size_t)(t - 1) * 8192 +
                         (size_t)(b0 + (tid >> 3)) * 64 + (tid & 7) * 8);

  // ---- poll h_{t-1}: 2 x 8B pieces per thread, selective re-load ----
  const unsigned long long* src = (const unsigned long long*)
      (h_all + (size_t)(t - 1) * 65536 + (size_t)(b0 + (tid >> 6)) * 512) +
      (size_t)(tid & 63) * 2;
  unsigned long long v0 = __hip_atomic_load(src,     __ATOMIC_RELAXED, __HIP_MEMORY_SCOPE_AGENT);
  unsigned long long v1 = __hip_atomic_load(src + 1, __ATOMIC_RELAXED, __HIP_MEMORY_SCOPE_AGENT);
  while (v0 == SENT || v1 == SENT) {
    if (v0 == SENT) v0 = __hip_atomic_load(src,     __ATOMIC_RELAXED, __HIP_MEMORY_SCOPE_AGENT);
    if (v1 == SENT) v1 = __hip_atomic_load(src + 1, __ATOMIC_RELAXED, __HIP_MEMORY_SCOPE_AGENT);
  }

  // ---- stage A (data already in registers from the poll) ----
  {
    unsigned long long* ad = (unsigned long long*)&A[tid >> 6][(tid & 63) * 8];
    ad[0] = v0; ad[1] = v1;
  }
  if (MAIN && tid < 128)
    *(uint4*)(&A[tid >> 3][512 + (tid & 7) * 8]) = xv;
  __syncthreads();

  // ---- MFMA: wave (gate, fsub); bias pre-loaded into accumulator ----
  if (MAIN || gate != 1) {
    f32x4 a0 = {bv, bv, bv, bv}, a1 = {0.f, 0.f, 0.f, 0.f};
    const __bf16* arow = &A[n16][quad * 8];
    #pragma unroll
    for (int kc = 0; kc < (MAIN ? 18 : 16); ++kc) {
      bf16x8 af = *(const bf16x8*)(arow + kc * 32);
      if (kc & 1) a1 = __builtin_amdgcn_mfma_f32_16x16x32_bf16(af, wf[kc], a1, 0, 0, 0);
      else        a0 = __builtin_amdgcn_mfma_f32_16x16x32_bf16(af, wf[kc], a0, 0, 0, 0);
    }
    a0 += a1;
    #pragma unroll
    for (int r = 0; r < 4; ++r)
      ex[gate][fsub * 16 + n16][quad * 4 + r] = a0[r];   // [gate][feat 0..63][batch]
  }
  __syncthreads();

  // ---- gates + publish: tid<256, one 8B piece (4 feats x 1 batch) ----
  if (tid < 256) {
    const int em = tid >> 4, p = tid & 15;
    unsigned long long pk = 0;
    #pragma unroll
    for (int j = 0; j < 4; ++j) {
      const int ef = p * 4 + j;
      float ig = sigm(ex[0][ef][em]);
      float gg = tanh_fast(ex[2][ef][em]);
      float og = sigm(ex[3][ef][em]);
      float c2;
      if (MAIN) { float fg = sigm(ex[1][ef][em]); c2 = fg * creg[j] + ig * gg; creg[j] = c2; }
      else      { c2 = ig * gg; }               // AR: zero state
      float h2 = og * tanh_fast(c2);
      __bf16 hb = (__bf16)h2;
      pk |= (unsigned long long)__builtin_bit_cast(unsigned short, hb) << (16 * j);
    }
    unsigned long long* dst = (unsigned long long*)
        (h_all + (size_t)t * 65536 + (size_t)(b0 + em) * 512 + f0) + p;
    __hip_atomic_store(dst, pk, __ATOMIC_RELAXED, __HIP_MEMORY_SCOPE_AGENT);
  }
  // no trailing barrier needed: next step's A writes race only with ex reads
  // (different LDS regions); ex reuse is ordered by the two syncs above.
}

__global__ void __launch_bounds__(1024, 4)
lstm_persist(const __bf16* __restrict__ xT, const __bf16* __restrict__ Wcat,
             const __bf16* __restrict__ Wih_bf, const float* __restrict__ b2,
             const float* __restrict__ b_ar, __bf16* __restrict__ h_all)
{
  const int bid = blockIdx.x;                  // 64 blocks
  const int g = bid & 7, sub = bid >> 3;       // group g: blocks {g, 8+g, ...}
  const int b0 = g * 16, f0 = sub * 64;
  const int tid = threadIdx.x;
  const int wv = tid >> 6, lane = tid & 63;
  const int n16 = lane & 15, quad = lane >> 4;
  const int gate = wv & 3, fsub = wv >> 2;

  __shared__ __align__(16) __bf16 A[16][584];  // 16 batch rows x (512 h + 64 x + pad)
  __shared__ float ex[4][64][17];              // gate exchange

  // persistent weight fragments (VGPR-resident): row = gate*512+f0+fsub*16+n16
  bf16x8 wf[18];
  {
    const __bf16* wrow = Wcat + (size_t)(gate * 512 + f0 + fsub * 16 + n16) * 576 + quad * 8;
    #pragma unroll
    for (int kc = 0; kc < 18; ++kc) wf[kc] = *(const bf16x8*)(wrow + kc * 32);
  }
  float bvm = b2[gate * 512 + f0 + fsub * 16 + n16];

  f32x4 creg = {0.f, 0.f, 0.f, 0.f};   // cell state c[b0+em][f0+p*4+j] (tid<256)

  for (unsigned t = 1; t <= 512; ++t)
    lstm_step<true>(t, tid, wv, lane, b0, f0, wf, bvm, h_all, xT, creg, A, ex);

  { // AR phase: h feeds Wih with zero recurrent state
    const __bf16* wrow = Wih_bf + (size_t)(gate * 512 + f0 + fsub * 16 + n16) * 512 + quad * 8;
    #pragma unroll
    for (int kc = 0; kc < 16; ++kc) wf[kc] = *(const bf16x8*)(wrow + kc * 32);
  }
  float bva = b_ar[gate * 512 + f0 + fsub * 16 + n16];
  for (unsigned t = 513; t <= 704; ++t)
    lstm_step<false>(t, tid, wv, lane, b0, f0, wf, bva, h_all, xT, creg, A, ex);
}

// ---------------------------------------------------------------------------
// final_proj: out[b][j][c] = h_slot[j+2][b][:] @ dec_W.T + dec_b, j=0..702.
// ---------------------------------------------------------------------------
__global__ void __launch_bounds__(256)
final_proj(const __bf16* __restrict__ h_all, const __bf16* __restrict__ decW_bf,
           const float* __restrict__ decb, float* __restrict__ out)
{
  const int bi = blockIdx.x;               // 0..702
  const int tid = threadIdx.x;
  const int wv = tid >> 6, lane = tid & 63;
  const int n16 = lane & 15, quad = lane >> 4;
  const size_t r0 = 256 + (size_t)bi * 128 + (size_t)wv * 32;

  f32x4 acc[2][4];
  #pragma unroll
  for (int mt = 0; mt < 2; ++mt)
    #pragma unroll
    for (int nt = 0; nt < 4; ++nt) acc[mt][nt] = f32x4{0.f, 0.f, 0.f, 0.f};

  const __bf16* arow0 = h_all + (r0 + n16) * 512 + quad * 8;
  const __bf16* arow1 = arow0 + 16 * 512;
  const __bf16* brow  = decW_bf + (size_t)n16 * 512 + quad * 8;

  #pragma unroll
  for (int kc = 0; kc < 16; ++kc) {
    bf16x8 a0 = *(const bf16x8*)(arow0 + kc * 32);
    bf16x8 a1 = *(const bf16x8*)(arow1 + kc * 32);
    #pragma unroll
    for (int nt = 0; nt < 4; ++nt) {
      bf16x8 b = *(const bf16x8*)(brow + (size_t)nt * 8192 + kc * 32);
      acc[0][nt] = __builtin_amdgcn_mfma_f32_16x16x32_bf16(a0, b, acc[0][nt], 0, 0, 0);
      acc[1][nt] = __builtin_amdgcn_mfma_f32_16x16x32_bf16(a1, b, acc[1][nt], 0, 0, 0);
    }
  }
  #pragma unroll
  for (int mt = 0; mt < 2; ++mt)
    #pragma unroll
    for (int nt = 0; nt < 4; ++nt)
      #pragma unroll
      for (int r = 0; r < 4; ++r) {
        size_t R = r0 + mt * 16 + quad * 4 + r;      // h_all row
        int slot = (int)(R >> 7), b = (int)(R & 127);
        int j = slot - 2;
        int c = nt * 16 + n16;
        out[((size_t)b * 703 + j) * 64 + c] = acc[mt][nt][r] + decb[c];
      }
}

// ---------------------------------------------------------------------------
extern "C" void kernel_launch(void* const* d_in, const int* in_sizes, int n_in,
                              void* d_out, int out_size, void* d_ws, size_t ws_size,
                              hipStream_t stream)
{
  const float* x    = (const float*)d_in[0];
  const float* encW = (const float*)d_in[1];
  const float* encb = (const float*)d_in[2];
  const float* Wih  = (const float*)d_in[3];
  const float* Whh  = (const float*)d_in[4];
  const float* bih  = (const float*)d_in[5];
  const float* bhh  = (const float*)d_in[6];
  const float* decW = (const float*)d_in[7];
  const float* decb = (const float*)d_in[8];
  float* out = (float*)d_out;

  if (ws_size < WS_NEEDED) return;

  char* ws = (char*)d_ws;
  __bf16* h_all   = (__bf16*)(ws + OFF_HALL);
  __bf16* Wcat    = (__bf16*)(ws + OFF_WCAT);
  __bf16* Wih_bf  = (__bf16*)(ws + OFF_WIH);
  __bf16* decW_bf = (__bf16*)(ws + OFF_DECW);
  __bf16* xT      = (__bf16*)(ws + OFF_XT);
  float*  b2      = (float*)(ws + OFF_B2);
  float*  b_ar    = (float*)(ws + OFF_BAR_);

  hipLaunchKernelGGL(setup0, dim3(2048), dim3(256), 0, stream,
                     x, Wih, Whh, bih, bhh, decW, xT, Wih_bf, Wcat, decW_bf,
                     b_ar, h_all);
  hipLaunchKernelGGL(setup1, dim3(2048), dim3(64), 0, stream,
                     Wih, encW, encb, bih, bhh, Wcat, b2);
  hipLaunchKernelGGL(lstm_persist, dim3(64), dim3(1024), 0, stream,
                     xT, Wcat, Wih_bf, b2, b_ar, h_all);
  hipLaunchKernelGGL(final_proj, dim3(703), dim3(256), 0, stream,
                     h_all, decW_bf, decb, out);
}